// Round 4
// baseline (943.534 us; speedup 1.0000x reference)
//
#include <hip/hip_runtime.h>
#include <math.h>
#include <stdint.h>

#define NBATCH 8
#define HGRID 128
#define DCH 256
#define NPTS 8192
#define INDIM 813
#define K0P 832
#define TOTROWS (NBATCH * NPTS)

typedef __attribute__((ext_vector_type(8))) short short8;
typedef __attribute__((ext_vector_type(16))) float f32x16;

// ---------- bf16 helpers ----------
__device__ __forceinline__ unsigned short bf16_rne(float f) {
  unsigned int u = __float_as_uint(f);
  u += 0x7fffu + ((u >> 16) & 1u);
  return (unsigned short)(u >> 16);
}
__device__ __forceinline__ float b2f(unsigned short h) {
  return __uint_as_float(((unsigned int)h) << 16);
}
__device__ __forceinline__ void split_bf16(float v, unsigned short& hi, unsigned short& lo) {
  hi = bf16_rne(v);
  lo = bf16_rne(v - b2f(hi));
}

__device__ __forceinline__ float gelu_f(float x) {
  float u = 0.7978845608028654f * (x + 0.044715f * x * x * x);
  float au = fabsf(u);
  float e = __expf(-2.0f * au);
  float t = 1.0f - 2.0f * e / (1.0f + e);
  t = copysignf(t, u);
  return 0.5f * x * (1.0f + t);
}

// ---------- async global->LDS 16B ----------
__device__ __forceinline__ void gload16(const void* g, void* l) {
  __builtin_amdgcn_global_load_lds(
      (const __attribute__((address_space(1))) unsigned int*)g,
      (__attribute__((address_space(3))) unsigned int*)l, 16, 0, 0);
}

// ---------------- ctx: gamma/beta ----------------
__global__ __launch_bounds__(256) void ctx_kernel(
    const float* __restrict__ cv, const float* __restrict__ cw,
    const float* __restrict__ cb, float* __restrict__ gb) {
  int b = blockIdx.x;
  int t = threadIdx.x;
  for (int half = 0; half < 2; ++half) {
    int j = half * 256 + t;
    float acc = cb[j];
    for (int k = 0; k < DCH; ++k)
      acc = fmaf(cv[b * DCH + k], cw[k * 512 + j], acc);
    if (j < 256) acc += 1.0f;
    gb[b * 512 + j] = acc;
  }
}

// ---------------- weight prep: transpose + split to bf16 hi/lo --------------
__global__ __launch_bounds__(256) void wprep0_kernel(const float* __restrict__ w0,
                                                     unsigned short* __restrict__ thi,
                                                     unsigned short* __restrict__ tlo) {
  int k = blockIdx.x;        // 0..831
  int n = threadIdx.x;       // 0..255
  float v = (k < INDIM) ? w0[(size_t)k * 256 + n] : 0.0f;
  unsigned short h, l;
  split_bf16(v, h, l);
  size_t o = (size_t)n * K0P + k;
  thi[o] = h; tlo[o] = l;
}
__global__ __launch_bounds__(256) void wpreph_kernel(const float* __restrict__ hw,
                                                     unsigned short* __restrict__ thi,
                                                     unsigned short* __restrict__ tlo) {
  int ik = blockIdx.x;       // i*256 + k
  int i = ik >> 8, k = ik & 255;
  int n = threadIdx.x;
  float v = hw[(size_t)ik * 256 + n];
  unsigned short h, l;
  split_bf16(v, h, l);
  size_t o = (size_t)i * 65536 + (size_t)n * 256 + k;
  thi[o] = h; tlo[o] = l;
}

// ---------------- antialiased triangle resize weights (jax.image.resize) ----
template <int SCALE>
__device__ __forceinline__ void mkw(int o, int nIn, float* w, int* ix) {
  const int TAPS = 2 * SCALE;
  float s = (float)(SCALE * o) + 0.5f * (float)(SCALE - 1);
  int j0 = SCALE * o + (SCALE - 2) / 2 - (SCALE - 1);
  float wsum = 0.f;
#pragma unroll
  for (int t = 0; t < TAPS; ++t) {
    int j = j0 + t;
    float wt = 1.0f - fabsf(s - (float)j) * (1.0f / (float)SCALE);
    bool valid = (j >= 0) && (j < nIn);
    wt = valid ? wt : 0.0f;
    ix[t] = valid ? j : 0;
    w[t] = wt;
    wsum += wt;
  }
  float inv = 1.0f / wsum;
#pragma unroll
  for (int t = 0; t < TAPS; ++t) w[t] *= inv;
}

// ---------------- separable resize: vertical then horizontal ----------------
template <int SCALE>
__global__ __launch_bounds__(256) void vpass_kernel(const float* __restrict__ g,
                                                    float* __restrict__ out) {
  const int HO = HGRID / SCALE;
  int pix = (blockIdx.x << 2) + (threadIdx.x >> 6);
  int lane = threadIdx.x & 63;
  int b = pix / (HO * HGRID);
  int rem = pix - b * (HO * HGRID);
  int oy = rem / HGRID, x = rem - (rem / HGRID) * HGRID;
  float wy[2 * SCALE]; int iy[2 * SCALE];
  mkw<SCALE>(oy, HGRID, wy, iy);
  float ax = 0.f, ay = 0.f, az = 0.f, aw = 0.f;
#pragma unroll
  for (int a = 0; a < 2 * SCALE; ++a) {
    if (wy[a] == 0.f) continue;
    const float4 v = *(const float4*)&g[((size_t)(b * HGRID + iy[a]) * HGRID + x) * DCH + lane * 4];
    ax = fmaf(wy[a], v.x, ax); ay = fmaf(wy[a], v.y, ay);
    az = fmaf(wy[a], v.z, az); aw = fmaf(wy[a], v.w, aw);
  }
  float4 r; r.x = ax; r.y = ay; r.z = az; r.w = aw;
  *(float4*)&out[(size_t)pix * DCH + lane * 4] = r;
}
template <int SCALE>
__global__ __launch_bounds__(256) void hpass_kernel(const float* __restrict__ v,
                                                    float* __restrict__ out) {
  const int HO = HGRID / SCALE, WO = HGRID / SCALE;
  int pix = (blockIdx.x << 2) + (threadIdx.x >> 6);
  int lane = threadIdx.x & 63;
  int b = pix / (HO * WO);
  int rem = pix - b * (HO * WO);
  int oy = rem / WO, ox = rem - (rem / WO) * WO;
  float wx[2 * SCALE]; int ix[2 * SCALE];
  mkw<SCALE>(ox, HGRID, wx, ix);
  float ax = 0.f, ay = 0.f, az = 0.f, aw = 0.f;
#pragma unroll
  for (int c = 0; c < 2 * SCALE; ++c) {
    if (wx[c] == 0.f) continue;
    const float4 t = *(const float4*)&v[((size_t)(b * HO + oy) * HGRID + ix[c]) * DCH + lane * 4];
    ax = fmaf(wx[c], t.x, ax); ay = fmaf(wx[c], t.y, ay);
    az = fmaf(wx[c], t.z, az); aw = fmaf(wx[c], t.w, aw);
  }
  float4 r; r.x = ax; r.y = ay; r.z = az; r.w = aw;
  *(float4*)&out[(size_t)pix * DCH + lane * 4] = r;
}

// ---------------- bilinear sample, split-bf16 write --------------------------
__device__ __forceinline__ void sample3(const float* __restrict__ g, int HW, int b,
                                        float cy, float cx, int lane,
                                        unsigned short* __restrict__ dhi,
                                        unsigned short* __restrict__ dlo) {
  float fm = (float)(HW - 1);
  float y = ((cy + 1.0f) * 0.5f) * fm;
  float x = ((cx + 1.0f) * 0.5f) * fm;
  float y0f = fminf(fmaxf(floorf(y), 0.0f), fm);
  float x0f = fminf(fmaxf(floorf(x), 0.0f), fm);
  int y0 = (int)y0f, x0 = (int)x0f;
  int y1 = min(y0 + 1, HW - 1), x1 = min(x0 + 1, HW - 1);
  float wy = y - y0f, wx = x - x0f;
  size_t bb = (size_t)b * HW * HW;
  const float4 v00 = *(const float4*)&g[(bb + (size_t)y0 * HW + x0) * DCH + lane * 4];
  const float4 v01 = *(const float4*)&g[(bb + (size_t)y0 * HW + x1) * DCH + lane * 4];
  const float4 v10 = *(const float4*)&g[(bb + (size_t)y1 * HW + x0) * DCH + lane * 4];
  const float4 v11 = *(const float4*)&g[(bb + (size_t)y1 * HW + x1) * DCH + lane * 4];
  float r[4];
  {
    float t0 = v00.x * (1.f - wx) + v01.x * wx, b0 = v10.x * (1.f - wx) + v11.x * wx;
    r[0] = t0 * (1.f - wy) + b0 * wy;
    float t1 = v00.y * (1.f - wx) + v01.y * wx, b1 = v10.y * (1.f - wx) + v11.y * wx;
    r[1] = t1 * (1.f - wy) + b1 * wy;
    float t2 = v00.z * (1.f - wx) + v01.z * wx, b2 = v10.z * (1.f - wx) + v11.z * wx;
    r[2] = t2 * (1.f - wy) + b2 * wy;
    float t3 = v00.w * (1.f - wx) + v01.w * wx, b3 = v10.w * (1.f - wx) + v11.w * wx;
    r[3] = t3 * (1.f - wy) + b3 * wy;
  }
  unsigned short h[4], l[4];
#pragma unroll
  for (int j = 0; j < 4; ++j) split_bf16(r[j], h[j], l[j]);
  ushort2 p;
  p.x = h[0]; p.y = h[1]; *(ushort2*)(dhi + lane * 4) = p;
  p.x = h[2]; p.y = h[3]; *(ushort2*)(dhi + lane * 4 + 2) = p;
  p.x = l[0]; p.y = l[1]; *(ushort2*)(dlo + lane * 4) = p;
  p.x = l[2]; p.y = l[3]; *(ushort2*)(dlo + lane * 4 + 2) = p;
}

// ---------------- assemble h0 row (split bf16 planes, pitch 832) ------------
__global__ __launch_bounds__(256) void assemble_kernel(
    const float* __restrict__ g0, const float* __restrict__ g1,
    const float* __restrict__ g2, const float* __restrict__ coords,
    const float* __restrict__ oracle, unsigned short* __restrict__ h0hi,
    unsigned short* __restrict__ h0lo, int row0, int nrows) {
  int lr = (blockIdx.x << 2) + (threadIdx.x >> 6);
  if (lr >= nrows) return;
  int lane = threadIdx.x & 63;
  int r = row0 + lr;
  int b = r >> 13, n = r & (NPTS - 1);
  float cy = coords[2 * n], cx = coords[2 * n + 1];
  unsigned short* rhi = h0hi + (size_t)lr * K0P;
  unsigned short* rlo = h0lo + (size_t)lr * K0P;
  if (lane < 45) {
    float val; int pos;
    if (lane < 2) { val = (lane == 0) ? cy : cx; pos = lane; }
    else if (lane < 42) {
      int q = lane - 2, f = q >> 2, m = q & 3;
      float ang = ((m & 1) ? cx : cy) * ldexpf(3.14159274101257324f, f);
      val = (m < 2) ? sinf(ang) : cosf(ang);
      pos = lane;
    } else { pos = 810 + (lane - 42); val = oracle[((size_t)b * NPTS + n) * 3 + (lane - 42)]; }
    unsigned short h, l; split_bf16(val, h, l);
    rhi[pos] = h; rlo[pos] = l;
  } else {
    int pos = INDIM + (lane - 45);  // 813..831
    rhi[pos] = 0; rlo[pos] = 0;
  }
  sample3(g0, 128, b, cy, cx, lane, rhi + 42, rlo + 42);
  sample3(g1, 64, b, cy, cx, lane, rhi + 42 + 256, rlo + 42 + 256);
  sample3(g2, 32, b, cy, cx, lane, rhi + 42 + 512, rlo + 42 + 512);
}

// ---------------- fused MLP v2: pipelined, B in registers --------------------
// 512 threads / 8 waves; 64 rows/block; A(h0) via 4-buffer LDS ring w/ counted
// vmcnt; weights global->VGPR (L2-hot); H resident in LDS with XOR swizzle.
#define MFMA(a, b, c) __builtin_amdgcn_mfma_f32_32x32x16_bf16((a), (b), (c), 0, 0, 0)

__global__ __launch_bounds__(512, 2) void fused_mlp(
    const unsigned short* __restrict__ Ahi, const unsigned short* __restrict__ Alo,
    const unsigned short* __restrict__ W0h, const unsigned short* __restrict__ W0l,
    const unsigned short* __restrict__ WHh, const unsigned short* __restrict__ WHl,
    const float* __restrict__ b0, const float* __restrict__ bh,
    const float* __restrict__ gbg, const float* __restrict__ ow,
    const float* __restrict__ ob, float* __restrict__ outp, int row0) {
  __shared__ alignas(16) unsigned short SAh[4][4][8][16][8];  // 32KB ring (hi)
  __shared__ alignas(16) unsigned short SAl[4][4][8][16][8];  // 32KB ring (lo)
  __shared__ alignas(16) unsigned short Hh[4][32][16][8];     // 32KB
  __shared__ alignas(16) unsigned short Hl[4][32][16][8];     // 32KB
  __shared__ float owL[768];
  __shared__ float obL[4];

  const int tid = threadIdx.x;
  const int lane = tid & 63;
  const int wid = tid >> 6;          // 0..7
  const int wm = wid >> 2;           // 0..1 (row half)
  const int wn = wid & 3;            // 0..3 (col quarter)
  const int ri = lane & 15;
  const int kq = lane >> 4;          // staging chunk 0..3
  const int rb = (lane >> 4) & 1;
  const int khalf = lane >> 5;
  const int wm2rb = wm * 2 + rb;
  const int mrow0 = blockIdx.x << 6;
  const int b = (row0 + mrow0) >> 13;
  const int colb = wn * 64 + (lane & 31);

  owL[tid] = ow[tid];
  if (tid < 256) owL[512 + tid] = ow[512 + tid];
  if (tid < 3) obL[tid] = ob[tid];

  float ga_r[2], be_r[2];
  {
    const float* gbb = gbg + ((size_t)b << 9);
    ga_r[0] = gbb[colb];       ga_r[1] = gbb[colb + 32];
    be_r[0] = gbb[256 + colb]; be_r[1] = gbb[256 + colb + 32];
  }

  // B base pointers for L0 (row = output col, pitch K0P)
  const size_t browb = (size_t)(wn * 64 + (lane & 31));
  const unsigned short* pb0h = W0h + (browb)*K0P + khalf * 8;
  const unsigned short* pb0l = W0l + (browb)*K0P + khalf * 8;
  const unsigned short* pb1h = pb0h + (size_t)32 * K0P;
  const unsigned short* pb1l = pb0l + (size_t)32 * K0P;

#define STAGE_A(ks, bufi)                                                      \
  {                                                                            \
    const int bA_ = (bufi);                                                    \
    const unsigned short* ap_ = (wid < 4) ? Ahi : Alo;                         \
    unsigned short* db_ = (wid < 4) ? &SAh[bA_][wid & 3][0][0][0]              \
                                    : &SAl[bA_][wid & 3][0][0][0];             \
    const unsigned short* s_ =                                                 \
        ap_ + (size_t)(mrow0 + (wid & 3) * 16 + ri) * K0P + (ks) + kq * 8;     \
    gload16(s_, db_);                                                          \
    gload16(s_ + 32, db_ + 512);                                               \
  }

  f32x16 acc0, acc1;
#pragma unroll
  for (int i = 0; i < 16; ++i) { acc0[i] = 0.f; acc1[i] = 0.f; }

  // ---- prologue: stage A(0..2) ----
  STAGE_A(0, 0)
  STAGE_A(64, 1)
  STAGE_A(128, 2)
  asm volatile("s_waitcnt vmcnt(4)" ::: "memory");  // A(0) landed; A(1),A(2) in flight
  __builtin_amdgcn_sched_barrier(0);
  __builtin_amdgcn_s_barrier();

  // ---- Layer 0: K=832, 13 steps of BK=64 ----
#pragma unroll 1
  for (int s = 0; s < 13; ++s) {
    const int koff = s * 64;
    short8 B0h[4], B0l[4], B1h[4], B1l[4];
#pragma unroll
    for (int t = 0; t < 4; ++t) {
      B0h[t] = *(const short8*)(pb0h + koff + t * 16);
      B0l[t] = *(const short8*)(pb0l + koff + t * 16);
      B1h[t] = *(const short8*)(pb1h + koff + t * 16);
      B1l[t] = *(const short8*)(pb1l + koff + t * 16);
    }
    __builtin_amdgcn_sched_barrier(0);
    {
      const int ks = (s + 3 <= 12) ? (s + 3) * 64 : 768;  // clamped tail stage
      STAGE_A(ks, (s + 3) & 3)
    }
    // drain B(s) (+ older A); keep A(s+3) in flight across the barrier
    asm volatile("s_waitcnt vmcnt(2)" ::: "memory");
    __builtin_amdgcn_sched_barrier(0);
    const int buf = s & 3;
#pragma unroll
    for (int t = 0; t < 4; ++t) {
      short8 ah = *(const short8*)&SAh[buf][wm2rb][t * 2 + khalf][ri][0];
      short8 al = *(const short8*)&SAl[buf][wm2rb][t * 2 + khalf][ri][0];
      acc0 = MFMA(ah, B0h[t], acc0); acc1 = MFMA(ah, B1h[t], acc1);
      acc0 = MFMA(ah, B0l[t], acc0); acc1 = MFMA(ah, B1l[t], acc1);
      acc0 = MFMA(al, B0h[t], acc0); acc1 = MFMA(al, B1h[t], acc1);
    }
    __builtin_amdgcn_sched_barrier(0);
    __builtin_amdgcn_s_barrier();
  }

#define EPILOGUE(bptr)                                                         \
  {                                                                            \
    _Pragma("unroll") for (int ni = 0; ni < 2; ++ni) {                         \
      int col_ = colb + ni * 32;                                               \
      float bi_ = (bptr)[col_];                                                \
      float ga_ = ga_r[ni], be_ = be_r[ni];                                    \
      const f32x16 av_ = ni ? acc1 : acc0;                                     \
      int kcw_ = col_ >> 3, jw_ = col_ & 7;                                    \
      int rsw_ = kcw_ & 15;                                                    \
      _Pragma("unroll") for (int reg = 0; reg < 16; ++reg) {                   \
        int riw_ = (reg & 3) + 8 * ((reg >> 2) & 1) + 4 * khalf;               \
        int rgw_ = wm * 2 + (reg >> 3);                                        \
        float v_ = gelu_f((av_[reg] + bi_) * ga_ + be_);                       \
        unsigned short hh_, ll_;                                               \
        split_bf16(v_, hh_, ll_);                                              \
        Hh[rgw_][kcw_][riw_ ^ rsw_][jw_] = hh_;                                \
        Hl[rgw_][kcw_][riw_ ^ rsw_][jw_] = ll_;                                \
      }                                                                        \
    }                                                                          \
  }

  EPILOGUE(b0)
  __builtin_amdgcn_sched_barrier(0);
  __builtin_amdgcn_s_barrier();

  // ---- Hidden layers: K=256, A from H (LDS), B from L2 into regs, no stage --
#pragma unroll 1
  for (int li = 0; li < 3; ++li) {
    const unsigned short* qh = WHh + (size_t)li * 65536 + (browb)*256 + khalf * 8;
    const unsigned short* ql = WHl + (size_t)li * 65536 + (browb)*256 + khalf * 8;
    const unsigned short* q1h = qh + (size_t)32 * 256;
    const unsigned short* q1l = ql + (size_t)32 * 256;
#pragma unroll
    for (int i = 0; i < 16; ++i) { acc0[i] = 0.f; acc1[i] = 0.f; }
#pragma unroll 2
    for (int s = 0; s < 4; ++s) {
      short8 B0h[4], B0l[4], B1h[4], B1l[4];
#pragma unroll
      for (int t = 0; t < 4; ++t) {
        B0h[t] = *(const short8*)(qh + s * 64 + t * 16);
        B0l[t] = *(const short8*)(ql + s * 64 + t * 16);
        B1h[t] = *(const short8*)(q1h + s * 64 + t * 16);
        B1l[t] = *(const short8*)(q1l + s * 64 + t * 16);
      }
#pragma unroll
      for (int t = 0; t < 4; ++t) {
        const int kcA = s * 8 + t * 2 + khalf;
        short8 ah = *(const short8*)&Hh[wm2rb][kcA][ri ^ (kcA & 15)][0];
        short8 al = *(const short8*)&Hl[wm2rb][kcA][ri ^ (kcA & 15)][0];
        acc0 = MFMA(ah, B0h[t], acc0); acc1 = MFMA(ah, B1h[t], acc1);
        acc0 = MFMA(ah, B0l[t], acc0); acc1 = MFMA(ah, B1l[t], acc1);
        acc0 = MFMA(al, B0h[t], acc0); acc1 = MFMA(al, B1h[t], acc1);
      }
    }
    __builtin_amdgcn_sched_barrier(0);
    __builtin_amdgcn_s_barrier();  // all reads of H done
    EPILOGUE(bh + li * 256)
    __builtin_amdgcn_sched_barrier(0);
    __builtin_amdgcn_s_barrier();  // H' visible
  }

  // ---- out projection: 256 -> 3 + tanh ----
  {
    int row = tid >> 3;
    int kc0 = (tid & 7) * 4;
    int rgo = row >> 4, rio = row & 15;
    float s0 = 0.f, s1 = 0.f, s2 = 0.f;
#pragma unroll
    for (int c = 0; c < 4; ++c) {
      const int kc = kc0 + c;
      short8 hh = *(const short8*)&Hh[rgo][kc][rio ^ (kc & 15)][0];
      short8 hl = *(const short8*)&Hl[rgo][kc][rio ^ (kc & 15)][0];
#pragma unroll
      for (int j = 0; j < 8; ++j) {
        float hv = b2f((unsigned short)hh[j]) + b2f((unsigned short)hl[j]);
        int k = kc * 8 + j;
        s0 = fmaf(hv, owL[k * 3 + 0], s0);
        s1 = fmaf(hv, owL[k * 3 + 1], s1);
        s2 = fmaf(hv, owL[k * 3 + 2], s2);
      }
    }
#pragma unroll
    for (int off = 1; off < 8; off <<= 1) {
      s0 += __shfl_xor(s0, off);
      s1 += __shfl_xor(s1, off);
      s2 += __shfl_xor(s2, off);
    }
    if ((tid & 7) == 0) {
      size_t r = (size_t)(row0 + mrow0 + row);
      outp[r * 3 + 0] = tanhf(s0 + obL[0]);
      outp[r * 3 + 1] = tanhf(s1 + obL[1]);
      outp[r * 3 + 2] = tanhf(s2 + obL[2]);
    }
  }
#undef STAGE_A
#undef EPILOGUE
}

extern "C" void kernel_launch(void* const* d_in, const int* in_sizes, int n_in,
                              void* d_out, int out_size, void* d_ws, size_t ws_size,
                              hipStream_t stream) {
  const float* feature_grid = (const float*)d_in[0];
  const float* context_vec = (const float*)d_in[1];
  const float* coords = (const float*)d_in[2];
  const float* oracle = (const float*)d_in[3];
  const float* mlp0_w = (const float*)d_in[4];
  const float* mlp0_b = (const float*)d_in[5];
  const float* mlp_hw = (const float*)d_in[6];
  const float* mlp_hb = (const float*)d_in[7];
  const float* ctx_w = (const float*)d_in[8];
  const float* ctx_b = (const float*)d_in[9];
  const float* out_w = (const float*)d_in[10];
  const float* out_b = (const float*)d_in[11];
  float* out = (float*)d_out;

  // ---- workspace layout (bytes) ----
  char* p = (char*)d_ws;
  float* gb = (float*)p;                 p += 8 * 512 * 4;
  unsigned short* w0t_hi = (unsigned short*)p; p += (size_t)256 * K0P * 2;
  unsigned short* w0t_lo = (unsigned short*)p; p += (size_t)256 * K0P * 2;
  unsigned short* wht_hi = (unsigned short*)p; p += (size_t)3 * 65536 * 2;
  unsigned short* wht_lo = (unsigned short*)p; p += (size_t)3 * 65536 * 2;
  float* lvl1 = (float*)p;               p += (size_t)8 * 64 * 64 * 256 * 4;
  float* lvl2 = (float*)p;               p += (size_t)8 * 32 * 32 * 256 * 4;
  float* vtmp = (float*)p;               p += (size_t)8 * 64 * 128 * 256 * 4;
  size_t fixed_bytes = (size_t)(p - (char*)d_ws);
  size_t per_row_bytes = (size_t)K0P * 2 * 2;  // h0 hi+lo only
  long long cap = 0;
  if (ws_size > fixed_bytes) cap = (long long)((ws_size - fixed_bytes) / per_row_bytes);
  if (cap > TOTROWS) cap = TOTROWS;
  cap &= ~127LL;
  if (cap < 128) cap = 128;
  unsigned short* h0hi = (unsigned short*)p;
  unsigned short* h0lo = h0hi + (size_t)cap * K0P;

  hipLaunchKernelGGL(ctx_kernel, dim3(8), dim3(256), 0, stream, context_vec, ctx_w, ctx_b, gb);
  hipLaunchKernelGGL(wprep0_kernel, dim3(K0P), dim3(256), 0, stream, mlp0_w, w0t_hi, w0t_lo);
  hipLaunchKernelGGL(wpreph_kernel, dim3(3 * 256), dim3(256), 0, stream, mlp_hw, wht_hi, wht_lo);
  hipLaunchKernelGGL((vpass_kernel<2>), dim3(8 * 64 * 128 / 4), dim3(256), 0, stream,
                     feature_grid, vtmp);
  hipLaunchKernelGGL((hpass_kernel<2>), dim3(8 * 64 * 64 / 4), dim3(256), 0, stream, vtmp, lvl1);
  hipLaunchKernelGGL((vpass_kernel<4>), dim3(8 * 32 * 128 / 4), dim3(256), 0, stream,
                     feature_grid, vtmp);
  hipLaunchKernelGGL((hpass_kernel<4>), dim3(8 * 32 * 32 / 4), dim3(256), 0, stream, vtmp, lvl2);

  int npass = (int)((TOTROWS + cap - 1) / cap);
  for (int ps = 0; ps < npass; ++ps) {
    int row0 = (int)((long long)ps * cap);
    int nrows = TOTROWS - row0;
    if (nrows > cap) nrows = (int)cap;
    int pb = (nrows + 3) >> 2;
    hipLaunchKernelGGL(assemble_kernel, dim3(pb), dim3(256), 0, stream, feature_grid,
                       lvl1, lvl2, coords, oracle, h0hi, h0lo, row0, nrows);
    hipLaunchKernelGGL(fused_mlp, dim3(nrows >> 6), dim3(512), 0, stream,
                       h0hi, h0lo, w0t_hi, w0t_lo, wht_hi, wht_lo,
                       mlp0_b, mlp_hb, gb, out_w, out_b, out, row0);
  }
}

// Round 5
// 619.410 us; speedup vs baseline: 1.5233x; 1.5233x over previous
//
#include <hip/hip_runtime.h>
#include <math.h>
#include <stdint.h>

#define NBATCH 8
#define HGRID 128
#define DCH 256
#define NPTS 8192
#define INDIM 813
#define K0P 832
#define TOTROWS (NBATCH * NPTS)

typedef __attribute__((ext_vector_type(8))) _Float16 half8;
typedef __attribute__((ext_vector_type(16))) float f32x16;

// ---------- fp16 helpers ----------
__device__ __forceinline__ unsigned short f2h(float v) {
  _Float16 h = (_Float16)v;
  union { _Float16 f; unsigned short u; } c; c.f = h; return c.u;
}
__device__ __forceinline__ float h2f(unsigned short u) {
  union { unsigned short u; _Float16 f; } c; c.u = u; return (float)c.f;
}
__device__ __forceinline__ void split_f16(float v, unsigned short& hi, unsigned short& lo) {
  _Float16 h = (_Float16)v;
  _Float16 l = (_Float16)(v - (float)h);
  union { _Float16 f; unsigned short u; } a, b; a.f = h; b.f = l;
  hi = a.u; lo = b.u;
}

__device__ __forceinline__ float gelu_f(float x) {
  float u = 0.7978845608028654f * (x + 0.044715f * x * x * x);
  float au = fabsf(u);
  float e = __expf(-2.0f * au);
  float t = 1.0f - 2.0f * e / (1.0f + e);
  t = copysignf(t, u);
  return 0.5f * x * (1.0f + t);
}

// ---------- async global->LDS 16B ----------
__device__ __forceinline__ void gload16(const void* g, void* l) {
  __builtin_amdgcn_global_load_lds(
      (const __attribute__((address_space(1))) unsigned int*)g,
      (__attribute__((address_space(3))) unsigned int*)l, 16, 0, 0);
}

// ---------------- ctx: gamma/beta ----------------
__global__ __launch_bounds__(256) void ctx_kernel(
    const float* __restrict__ cv, const float* __restrict__ cw,
    const float* __restrict__ cb, float* __restrict__ gb) {
  int b = blockIdx.x;
  int t = threadIdx.x;
  for (int half = 0; half < 2; ++half) {
    int j = half * 256 + t;
    float acc = cb[j];
    for (int k = 0; k < DCH; ++k)
      acc = fmaf(cv[b * DCH + k], cw[k * 512 + j], acc);
    if (j < 256) acc += 1.0f;
    gb[b * 512 + j] = acc;
  }
}

// ---------------- weight prep: transpose + split fp16 hi/lo ------------------
__global__ __launch_bounds__(256) void wprep0_kernel(const float* __restrict__ w0,
                                                     unsigned short* __restrict__ thi,
                                                     unsigned short* __restrict__ tlo) {
  int k = blockIdx.x;        // 0..831
  int n = threadIdx.x;       // 0..255
  float v = (k < INDIM) ? w0[(size_t)k * 256 + n] : 0.0f;
  unsigned short h, l;
  split_f16(v, h, l);
  size_t o = (size_t)n * K0P + k;
  thi[o] = h; tlo[o] = l;
}
__global__ __launch_bounds__(256) void wpreph_kernel(const float* __restrict__ hw,
                                                     unsigned short* __restrict__ thi,
                                                     unsigned short* __restrict__ tlo) {
  int ik = blockIdx.x;       // i*256 + k
  int i = ik >> 8, k = ik & 255;
  int n = threadIdx.x;
  float v = hw[(size_t)ik * 256 + n];
  unsigned short h, l;
  split_f16(v, h, l);
  size_t o = (size_t)i * 65536 + (size_t)n * 256 + k;
  thi[o] = h; tlo[o] = l;
}

// ---------------- antialiased triangle resize weights (jax.image.resize) ----
template <int SCALE>
__device__ __forceinline__ void mkw(int o, int nIn, float* w, int* ix) {
  const int TAPS = 2 * SCALE;
  float s = (float)(SCALE * o) + 0.5f * (float)(SCALE - 1);
  int j0 = SCALE * o + (SCALE - 2) / 2 - (SCALE - 1);
  float wsum = 0.f;
#pragma unroll
  for (int t = 0; t < TAPS; ++t) {
    int j = j0 + t;
    float wt = 1.0f - fabsf(s - (float)j) * (1.0f / (float)SCALE);
    bool valid = (j >= 0) && (j < nIn);
    wt = valid ? wt : 0.0f;
    ix[t] = valid ? j : 0;
    w[t] = wt;
    wsum += wt;
  }
  float inv = 1.0f / wsum;
#pragma unroll
  for (int t = 0; t < TAPS; ++t) w[t] *= inv;
}

// ---------------- separable resize: vertical (fp32) then horizontal (fp16) --
template <int SCALE>
__global__ __launch_bounds__(256) void vpass_kernel(const float* __restrict__ g,
                                                    float* __restrict__ out) {
  const int HO = HGRID / SCALE;
  int pix = (blockIdx.x << 2) + (threadIdx.x >> 6);
  int lane = threadIdx.x & 63;
  int b = pix / (HO * HGRID);
  int rem = pix - b * (HO * HGRID);
  int oy = rem / HGRID, x = rem - (rem / HGRID) * HGRID;
  float wy[2 * SCALE]; int iy[2 * SCALE];
  mkw<SCALE>(oy, HGRID, wy, iy);
  float ax = 0.f, ay = 0.f, az = 0.f, aw = 0.f;
#pragma unroll
  for (int a = 0; a < 2 * SCALE; ++a) {
    if (wy[a] == 0.f) continue;
    const float4 v = *(const float4*)&g[((size_t)(b * HGRID + iy[a]) * HGRID + x) * DCH + lane * 4];
    ax = fmaf(wy[a], v.x, ax); ay = fmaf(wy[a], v.y, ay);
    az = fmaf(wy[a], v.z, az); aw = fmaf(wy[a], v.w, aw);
  }
  float4 r; r.x = ax; r.y = ay; r.z = az; r.w = aw;
  *(float4*)&out[(size_t)pix * DCH + lane * 4] = r;
}
template <int SCALE>
__global__ __launch_bounds__(256) void hpass_kernel(const float* __restrict__ v,
                                                    unsigned short* __restrict__ out) {
  const int HO = HGRID / SCALE, WO = HGRID / SCALE;
  int pix = (blockIdx.x << 2) + (threadIdx.x >> 6);
  int lane = threadIdx.x & 63;
  int b = pix / (HO * WO);
  int rem = pix - b * (HO * WO);
  int oy = rem / WO, ox = rem - (rem / WO) * WO;
  float wx[2 * SCALE]; int ix[2 * SCALE];
  mkw<SCALE>(ox, HGRID, wx, ix);
  float ax = 0.f, ay = 0.f, az = 0.f, aw = 0.f;
#pragma unroll
  for (int c = 0; c < 2 * SCALE; ++c) {
    if (wx[c] == 0.f) continue;
    const float4 t = *(const float4*)&v[((size_t)(b * HO + oy) * HGRID + ix[c]) * DCH + lane * 4];
    ax = fmaf(wx[c], t.x, ax); ay = fmaf(wx[c], t.y, ay);
    az = fmaf(wx[c], t.z, az); aw = fmaf(wx[c], t.w, aw);
  }
  ushort4 r;
  r.x = f2h(ax); r.y = f2h(ay); r.z = f2h(az); r.w = f2h(aw);
  *(ushort4*)&out[(size_t)pix * DCH + lane * 4] = r;
}

// ---------------- bilinear sampling into fp16 h0 row -------------------------
__device__ __forceinline__ void sample3_f32(const float* __restrict__ g, int HW, int b,
                                            float cy, float cx, int lane,
                                            unsigned short* __restrict__ dst) {
  float fm = (float)(HW - 1);
  float y = ((cy + 1.0f) * 0.5f) * fm;
  float x = ((cx + 1.0f) * 0.5f) * fm;
  float y0f = fminf(fmaxf(floorf(y), 0.0f), fm);
  float x0f = fminf(fmaxf(floorf(x), 0.0f), fm);
  int y0 = (int)y0f, x0 = (int)x0f;
  int y1 = min(y0 + 1, HW - 1), x1 = min(x0 + 1, HW - 1);
  float wy = y - y0f, wx = x - x0f;
  size_t bb = (size_t)b * HW * HW;
  const float4 v00 = *(const float4*)&g[(bb + (size_t)y0 * HW + x0) * DCH + lane * 4];
  const float4 v01 = *(const float4*)&g[(bb + (size_t)y0 * HW + x1) * DCH + lane * 4];
  const float4 v10 = *(const float4*)&g[(bb + (size_t)y1 * HW + x0) * DCH + lane * 4];
  const float4 v11 = *(const float4*)&g[(bb + (size_t)y1 * HW + x1) * DCH + lane * 4];
  float r[4];
  r[0] = (v00.x*(1.f-wx)+v01.x*wx)*(1.f-wy) + (v10.x*(1.f-wx)+v11.x*wx)*wy;
  r[1] = (v00.y*(1.f-wx)+v01.y*wx)*(1.f-wy) + (v10.y*(1.f-wx)+v11.y*wx)*wy;
  r[2] = (v00.z*(1.f-wx)+v01.z*wx)*(1.f-wy) + (v10.z*(1.f-wx)+v11.z*wx)*wy;
  r[3] = (v00.w*(1.f-wx)+v01.w*wx)*(1.f-wy) + (v10.w*(1.f-wx)+v11.w*wx)*wy;
  ushort2 p;
  p.x = f2h(r[0]); p.y = f2h(r[1]); *(ushort2*)(dst + lane * 4) = p;
  p.x = f2h(r[2]); p.y = f2h(r[3]); *(ushort2*)(dst + lane * 4 + 2) = p;
}
__device__ __forceinline__ void sample3_f16(const unsigned short* __restrict__ g, int HW, int b,
                                            float cy, float cx, int lane,
                                            unsigned short* __restrict__ dst) {
  float fm = (float)(HW - 1);
  float y = ((cy + 1.0f) * 0.5f) * fm;
  float x = ((cx + 1.0f) * 0.5f) * fm;
  float y0f = fminf(fmaxf(floorf(y), 0.0f), fm);
  float x0f = fminf(fmaxf(floorf(x), 0.0f), fm);
  int y0 = (int)y0f, x0 = (int)x0f;
  int y1 = min(y0 + 1, HW - 1), x1 = min(x0 + 1, HW - 1);
  float wy = y - y0f, wx = x - x0f;
  size_t bb = (size_t)b * HW * HW;
  const ushort4 u00 = *(const ushort4*)&g[(bb + (size_t)y0 * HW + x0) * DCH + lane * 4];
  const ushort4 u01 = *(const ushort4*)&g[(bb + (size_t)y0 * HW + x1) * DCH + lane * 4];
  const ushort4 u10 = *(const ushort4*)&g[(bb + (size_t)y1 * HW + x0) * DCH + lane * 4];
  const ushort4 u11 = *(const ushort4*)&g[(bb + (size_t)y1 * HW + x1) * DCH + lane * 4];
  float r[4];
  r[0] = (h2f(u00.x)*(1.f-wx)+h2f(u01.x)*wx)*(1.f-wy) + (h2f(u10.x)*(1.f-wx)+h2f(u11.x)*wx)*wy;
  r[1] = (h2f(u00.y)*(1.f-wx)+h2f(u01.y)*wx)*(1.f-wy) + (h2f(u10.y)*(1.f-wx)+h2f(u11.y)*wx)*wy;
  r[2] = (h2f(u00.z)*(1.f-wx)+h2f(u01.z)*wx)*(1.f-wy) + (h2f(u10.z)*(1.f-wx)+h2f(u11.z)*wx)*wy;
  r[3] = (h2f(u00.w)*(1.f-wx)+h2f(u01.w)*wx)*(1.f-wy) + (h2f(u10.w)*(1.f-wx)+h2f(u11.w)*wx)*wy;
  ushort2 p;
  p.x = f2h(r[0]); p.y = f2h(r[1]); *(ushort2*)(dst + lane * 4) = p;
  p.x = f2h(r[2]); p.y = f2h(r[3]); *(ushort2*)(dst + lane * 4 + 2) = p;
}

// ---------------- assemble h0 row (fp16, pitch 832) --------------------------
__global__ __launch_bounds__(256) void assemble_kernel(
    const float* __restrict__ g0, const unsigned short* __restrict__ g1,
    const unsigned short* __restrict__ g2, const float* __restrict__ coords,
    const float* __restrict__ oracle, unsigned short* __restrict__ h0,
    int row0, int nrows) {
  int lr = (blockIdx.x << 2) + (threadIdx.x >> 6);
  if (lr >= nrows) return;
  int lane = threadIdx.x & 63;
  int r = row0 + lr;
  int b = r >> 13, n = r & (NPTS - 1);
  float cy = coords[2 * n], cx = coords[2 * n + 1];
  unsigned short* row = h0 + (size_t)lr * K0P;
  if (lane < 45) {
    float val; int pos;
    if (lane < 2) { val = (lane == 0) ? cy : cx; pos = lane; }
    else if (lane < 42) {
      int q = lane - 2, f = q >> 2, m = q & 3;
      float ang = ((m & 1) ? cx : cy) * ldexpf(3.14159274101257324f, f);
      val = (m < 2) ? sinf(ang) : cosf(ang);
      pos = lane;
    } else { pos = 810 + (lane - 42); val = oracle[((size_t)b * NPTS + n) * 3 + (lane - 42)]; }
    row[pos] = f2h(val);
  } else {
    row[INDIM + (lane - 45)] = 0;  // 813..831 zero pad
  }
  sample3_f32(g0, 128, b, cy, cx, lane, row + 42);
  sample3_f16(g1, 64, b, cy, cx, lane, row + 42 + 256);
  sample3_f16(g2, 32, b, cy, cx, lane, row + 42 + 512);
}

// ---------------- fp16 split-weight MFMA GEMM (2-phase pipelined) ------------
// C[r,n] = gelu((sum_k A[r,k]*(Wh[n,k]+Wl[n,k]) + bias[n]) * gamma + beta), fp16 out
#define MFMA16(a, b, c) __builtin_amdgcn_mfma_f32_32x32x16_f16((a), (b), (c), 0, 0, 0)

__global__ __launch_bounds__(256, 2) void gemm_f16(
    const unsigned short* __restrict__ A, int lda,
    const unsigned short* __restrict__ Wh, const unsigned short* __restrict__ Wl, int ldb,
    int K, const float* __restrict__ bias, const float* __restrict__ gb,
    unsigned short* __restrict__ C, int row0) {
  __shared__ alignas(16) unsigned short SA[2][8][4][16][8];     // 16 KB
  __shared__ alignas(16) unsigned short SB[2][2][8][4][16][8];  // 32 KB
  const int tid = threadIdx.x;
  const int lane = tid & 63;
  const int wid = tid >> 6;        // 0..3
  const int wm = wid >> 1, wn = wid & 1;
  const int ri = lane & 15;
  const int kq = lane >> 4;        // staging chunk 0..3
  const int rb = (lane >> 4) & 1;
  const int khalf = lane >> 5;
  const int m0 = blockIdx.x << 7;
  const int n0 = blockIdx.y << 7;

  f32x16 acc[2][2];
#pragma unroll
  for (int mi = 0; mi < 2; ++mi)
#pragma unroll
    for (int ni = 0; ni < 2; ++ni)
#pragma unroll
      for (int i = 0; i < 16; ++i) acc[mi][ni][i] = 0.f;

#define STAGE(bufi, kk)                                                          \
  {                                                                              \
    const unsigned short* sa_ =                                                  \
        A + (size_t)(m0 + (wid * 2) * 16 + ri) * lda + (kk) + kq * 8;            \
    gload16(sa_, &SA[bufi][wid * 2 + 0][0][0][0]);                               \
    gload16(sa_ + (size_t)16 * lda, &SA[bufi][wid * 2 + 1][0][0][0]);            \
    const unsigned short* sh_ =                                                  \
        Wh + (size_t)(n0 + (wid * 2) * 16 + ri) * ldb + (kk) + kq * 8;           \
    gload16(sh_, &SB[bufi][0][wid * 2 + 0][0][0][0]);                            \
    gload16(sh_ + (size_t)16 * ldb, &SB[bufi][0][wid * 2 + 1][0][0][0]);         \
    const unsigned short* sl_ =                                                  \
        Wl + (size_t)(n0 + (wid * 2) * 16 + ri) * ldb + (kk) + kq * 8;           \
    gload16(sl_, &SB[bufi][1][wid * 2 + 0][0][0][0]);                            \
    gload16(sl_ + (size_t)16 * ldb, &SB[bufi][1][wid * 2 + 1][0][0][0]);         \
  }

  const int nt = K >> 5;
  STAGE(0, 0)
  __syncthreads();
#pragma unroll 1
  for (int t = 0; t < nt; ++t) {
    if (t + 1 < nt) STAGE((t + 1) & 1, (t + 1) << 5)
    const int buf = t & 1;
    half8 a[2][2], bh[2][2], bl[2][2];
#pragma unroll
    for (int mi = 0; mi < 2; ++mi)
#pragma unroll
      for (int tt = 0; tt < 2; ++tt)
        a[mi][tt] = *(const half8*)&SA[buf][wm * 4 + mi * 2 + rb][tt * 2 + khalf][ri][0];
#pragma unroll
    for (int ni = 0; ni < 2; ++ni)
#pragma unroll
      for (int tt = 0; tt < 2; ++tt) {
        bh[ni][tt] = *(const half8*)&SB[buf][0][wn * 4 + ni * 2 + rb][tt * 2 + khalf][ri][0];
        bl[ni][tt] = *(const half8*)&SB[buf][1][wn * 4 + ni * 2 + rb][tt * 2 + khalf][ri][0];
      }
#pragma unroll
    for (int tt = 0; tt < 2; ++tt)
#pragma unroll
      for (int mi = 0; mi < 2; ++mi)
#pragma unroll
        for (int ni = 0; ni < 2; ++ni) {
          acc[mi][ni] = MFMA16(a[mi][tt], bh[ni][tt], acc[mi][ni]);
          acc[mi][ni] = MFMA16(a[mi][tt], bl[ni][tt], acc[mi][ni]);
        }
    __syncthreads();
  }

  const int bidx = (row0 + m0) >> 13;
  const float* gbb = gb + (bidx << 9);
#pragma unroll
  for (int ni = 0; ni < 2; ++ni) {
    const int col = n0 + wn * 64 + ni * 32 + (lane & 31);
    const float bi = bias[col], ga = gbb[col], be = gbb[256 + col];
#pragma unroll
    for (int mi = 0; mi < 2; ++mi) {
      const f32x16 av = acc[mi][ni];
#pragma unroll
      for (int r = 0; r < 16; ++r) {
        const int row = m0 + wm * 64 + mi * 32 + (r & 3) + ((r >> 2) << 3) + 4 * khalf;
        float v = gelu_f((av[r] + bi) * ga + be);
        C[(size_t)row * 256 + col] = f2h(v);
      }
    }
  }
#undef STAGE
}

// ---------------- final 256 -> 3 + tanh --------------------------------------
__global__ __launch_bounds__(256) void out_kernel(
    const unsigned short* __restrict__ Hf, const float* __restrict__ ow,
    const float* __restrict__ ob, float* __restrict__ out, int row0, int nrows) {
  int lr = (blockIdx.x << 2) + (threadIdx.x >> 6);
  if (lr >= nrows) return;
  int lane = threadIdx.x & 63;
  ushort4 h = *(const ushort4*)&Hf[(size_t)lr * 256 + (lane << 2)];
  float hv[4] = {h2f(h.x), h2f(h.y), h2f(h.z), h2f(h.w)};
  float s0 = 0.f, s1 = 0.f, s2 = 0.f;
#pragma unroll
  for (int j = 0; j < 4; ++j) {
    int k = (lane << 2) + j;
    s0 = fmaf(hv[j], ow[k * 3 + 0], s0);
    s1 = fmaf(hv[j], ow[k * 3 + 1], s1);
    s2 = fmaf(hv[j], ow[k * 3 + 2], s2);
  }
#pragma unroll
  for (int off = 32; off > 0; off >>= 1) {
    s0 += __shfl_down(s0, off);
    s1 += __shfl_down(s1, off);
    s2 += __shfl_down(s2, off);
  }
  if (lane == 0) {
    size_t r = (size_t)(row0 + lr);
    out[r * 3 + 0] = tanhf(s0 + ob[0]);
    out[r * 3 + 1] = tanhf(s1 + ob[1]);
    out[r * 3 + 2] = tanhf(s2 + ob[2]);
  }
}

extern "C" void kernel_launch(void* const* d_in, const int* in_sizes, int n_in,
                              void* d_out, int out_size, void* d_ws, size_t ws_size,
                              hipStream_t stream) {
  const float* feature_grid = (const float*)d_in[0];
  const float* context_vec = (const float*)d_in[1];
  const float* coords = (const float*)d_in[2];
  const float* oracle = (const float*)d_in[3];
  const float* mlp0_w = (const float*)d_in[4];
  const float* mlp0_b = (const float*)d_in[5];
  const float* mlp_hw = (const float*)d_in[6];
  const float* mlp_hb = (const float*)d_in[7];
  const float* ctx_w = (const float*)d_in[8];
  const float* ctx_b = (const float*)d_in[9];
  const float* out_w = (const float*)d_in[10];
  const float* out_b = (const float*)d_in[11];
  float* out = (float*)d_out;

  // ---- workspace layout (bytes) ----
  char* p = (char*)d_ws;
  float* gb = (float*)p;                 p += 8 * 512 * 4;
  unsigned short* w0t_hi = (unsigned short*)p; p += (size_t)256 * K0P * 2;
  unsigned short* w0t_lo = (unsigned short*)p; p += (size_t)256 * K0P * 2;
  unsigned short* wht_hi = (unsigned short*)p; p += (size_t)3 * 65536 * 2;
  unsigned short* wht_lo = (unsigned short*)p; p += (size_t)3 * 65536 * 2;
  unsigned short* lvl1 = (unsigned short*)p;   p += (size_t)8 * 64 * 64 * 256 * 2;
  unsigned short* lvl2 = (unsigned short*)p;   p += (size_t)8 * 32 * 32 * 256 * 2;
  float* vtmp = (float*)p;               p += (size_t)8 * 64 * 128 * 256 * 4;
  size_t fixed_bytes = (size_t)(p - (char*)d_ws);
  size_t per_row_bytes = (size_t)(K0P + 256 + 256) * 2;  // h0 + hA + hB fp16
  long long cap = 0;
  if (ws_size > fixed_bytes) cap = (long long)((ws_size - fixed_bytes) / per_row_bytes);
  if (cap > TOTROWS) cap = TOTROWS;
  cap &= ~127LL;
  if (cap < 128) cap = 128;
  unsigned short* h0 = (unsigned short*)p;
  unsigned short* hA = h0 + (size_t)cap * K0P;
  unsigned short* hB = hA + (size_t)cap * 256;

  hipLaunchKernelGGL(ctx_kernel, dim3(8), dim3(256), 0, stream, context_vec, ctx_w, ctx_b, gb);
  hipLaunchKernelGGL(wprep0_kernel, dim3(K0P), dim3(256), 0, stream, mlp0_w, w0t_hi, w0t_lo);
  hipLaunchKernelGGL(wpreph_kernel, dim3(3 * 256), dim3(256), 0, stream, mlp_hw, wht_hi, wht_lo);
  hipLaunchKernelGGL((vpass_kernel<2>), dim3(8 * 64 * 128 / 4), dim3(256), 0, stream,
                     feature_grid, vtmp);
  hipLaunchKernelGGL((hpass_kernel<2>), dim3(8 * 64 * 64 / 4), dim3(256), 0, stream, vtmp, lvl1);
  hipLaunchKernelGGL((vpass_kernel<4>), dim3(8 * 32 * 128 / 4), dim3(256), 0, stream,
                     feature_grid, vtmp);
  hipLaunchKernelGGL((hpass_kernel<4>), dim3(8 * 32 * 32 / 4), dim3(256), 0, stream, vtmp, lvl2);

  int npass = (int)((TOTROWS + cap - 1) / cap);
  for (int ps = 0; ps < npass; ++ps) {
    int row0 = (int)((long long)ps * cap);
    int nrows = TOTROWS - row0;
    if (nrows > cap) nrows = (int)cap;
    int pb = (nrows + 3) >> 2;
    hipLaunchKernelGGL(assemble_kernel, dim3(pb), dim3(256), 0, stream, feature_grid,
                       lvl1, lvl2, coords, oracle, h0, row0, nrows);
    dim3 ggrid((nrows + 127) >> 7, 2);
    hipLaunchKernelGGL(gemm_f16, ggrid, dim3(256), 0, stream, h0, K0P,
                       w0t_hi, w0t_lo, K0P, K0P, mlp0_b, gb, hA, row0);
    hipLaunchKernelGGL(gemm_f16, ggrid, dim3(256), 0, stream, hA, 256,
                       wht_hi + 0 * 65536, wht_lo + 0 * 65536, 256, 256,
                       mlp_hb + 0, gb, hB, row0);
    hipLaunchKernelGGL(gemm_f16, ggrid, dim3(256), 0, stream, hB, 256,
                       wht_hi + 1 * 65536, wht_lo + 1 * 65536, 256, 256,
                       mlp_hb + 256, gb, hA, row0);
    hipLaunchKernelGGL(gemm_f16, ggrid, dim3(256), 0, stream, hA, 256,
                       wht_hi + 2 * 65536, wht_lo + 2 * 65536, 256, 256,
                       mlp_hb + 512, gb, hB, row0);
    hipLaunchKernelGGL(out_kernel, dim3(pb), dim3(256), 0, stream, hB, out_w, out_b,
                       out, row0, nrows);
  }
}